// Round 4
// baseline (105.477 us; speedup 1.0000x reference)
//
#include <hip/hip_runtime.h>
#include <hip/hip_bf16.h>
#include <math.h>

#define BB   2
#define SS   1024
#define HIDD 768
#define NHH  12
#define HDD  64

typedef float f32x4 __attribute__((ext_vector_type(4)));
typedef short bf8   __attribute__((ext_vector_type(8)));   // 8 bf16 (bit pattern)
typedef unsigned short u16;
typedef u16 u16x8 __attribute__((ext_vector_type(8)));
typedef u16 u16x4 __attribute__((ext_vector_type(4)));

__device__ __forceinline__ u16 f2bf(float x) {  // RNE f32->bf16
  unsigned int u = __float_as_uint(x);
  u += 0x7fffu + ((u >> 16) & 1u);
  return (u16)(u >> 16);
}

// Swizzled fragment read from a [R][64] bf16 LDS tile (XOR swizzle, 8-elem
// granularity). row = M/N index; kc = starting k element (multiple of 8).
__device__ __forceinline__ bf8 ldfrag(const u16* t, int row, int kc) {
  return *(const bf8*)&t[row * 64 + (kc ^ ((row & 7) << 3))];
}

// ---------------------------------------------------------------------------
// Prep: X f32 -> bf16 (same layout).
// ---------------------------------------------------------------------------
__global__ __launch_bounds__(256) void xconv_kernel(const float* __restrict__ X,
                                                    u16* __restrict__ Xb) {
  int i = (blockIdx.x * 256 + threadIdx.x) * 8;
  float4 a = *(const float4*)&X[i];
  float4 b = *(const float4*)&X[i + 4];
  u16x8 o;
  o[0] = f2bf(a.x); o[1] = f2bf(a.y); o[2] = f2bf(a.z); o[3] = f2bf(a.w);
  o[4] = f2bf(b.x); o[5] = f2bf(b.y); o[6] = f2bf(b.z); o[7] = f2bf(b.w);
  *(u16x8*)&Xb[i] = o;
}

// ---------------------------------------------------------------------------
// Prep: W [k][n] f32 (x3) -> Wt [3*768 rows n][768 cols k] bf16 (transposed).
// ---------------------------------------------------------------------------
__global__ __launch_bounds__(256) void wtconv_kernel(
    const float* __restrict__ Wq, const float* __restrict__ Wk,
    const float* __restrict__ Wv, u16* __restrict__ Wt) {
  const int zi = blockIdx.z;
  const float* __restrict__ W = (zi == 0) ? Wq : (zi == 1 ? Wk : Wv);
  const int n0 = blockIdx.x * 64;
  const int k0 = blockIdx.y * 64;
  __shared__ float t[64][65];
  const int tid = threadIdx.x;
  {
    const int kl = tid >> 4;
    const int nl = (tid & 15) * 4;
#pragma unroll
    for (int p = 0; p < 4; ++p) {
      float4 v = *(const float4*)&W[(size_t)(k0 + kl + 16 * p) * HIDD + n0 + nl];
      t[kl + 16 * p][nl + 0] = v.x;
      t[kl + 16 * p][nl + 1] = v.y;
      t[kl + 16 * p][nl + 2] = v.z;
      t[kl + 16 * p][nl + 3] = v.w;
    }
  }
  __syncthreads();
  {
    const int nl = tid >> 4;
    const int cl = (tid & 15) * 4;
#pragma unroll
    for (int p = 0; p < 4; ++p) {
      const int n = nl + 16 * p;
      u16x4 o;
      o[0] = f2bf(t[cl + 0][n]);
      o[1] = f2bf(t[cl + 1][n]);
      o[2] = f2bf(t[cl + 2][n]);
      o[3] = f2bf(t[cl + 3][n]);
      *(u16x4*)&Wt[(size_t)(zi * HIDD + n0 + n) * HIDD + k0 + cl] = o;
    }
  }
}

// ---------------------------------------------------------------------------
// Prep: dist_emb f32 -> bf16.
// ---------------------------------------------------------------------------
__global__ __launch_bounds__(256) void econv_kernel(const float* __restrict__ demb,
                                                    u16* __restrict__ eb) {
  int i = (blockIdx.x * 256 + threadIdx.x) * 8;
  if (i < 2047 * HDD) {
    float4 a = *(const float4*)&demb[i];
    float4 b = *(const float4*)&demb[i + 4];
    u16x8 o;
    o[0] = f2bf(a.x); o[1] = f2bf(a.y); o[2] = f2bf(a.z); o[3] = f2bf(a.w);
    o[4] = f2bf(b.x); o[5] = f2bf(b.y); o[6] = f2bf(b.z); o[7] = f2bf(b.w);
    *(u16x8*)&eb[i] = o;
  }
}

// ---------------------------------------------------------------------------
// Fused QKV MFMA GEMM: [2048,768]bf16 @ Wt^T -> N=2304 (Q|K|V).
// 64x128 tile, BK=64, 4 waves (2x2), wave tile 32x64. 576 blocks.
// Q,K epilogue: swapped-operand (transposed frags) -> row-major [bh][s][d].
// V epilogue: normal order -> V^T [bh][d][s].
// ---------------------------------------------------------------------------
__global__ __launch_bounds__(256) void qkv_mfma_kernel(
    const u16* __restrict__ Xb,   // [2048][768]
    const u16* __restrict__ Wt,   // [2304][768]
    const float* __restrict__ bq, const float* __restrict__ bk,
    const float* __restrict__ bv,
    u16* __restrict__ qb, u16* __restrict__ kb, u16* __restrict__ vt) {
  const int bn = blockIdx.x;   // 0..17  (128 N-cols each)
  const int bm = blockIdx.y;   // 0..31  (64 M-rows each)
  const int zi = bn / 6;

  __shared__ u16 As[64 * 64];
  __shared__ u16 Bs[128 * 64];

  const int tid  = threadIdx.x;
  const int lane = tid & 63;
  const int w    = tid >> 6;
  const int g    = lane >> 4;
  const int ln   = lane & 15;
  const int wm   = (w >> 1) * 32;
  const int wn   = (w & 1) * 64;

  f32x4 acc[2][4] = {};

  const int srow = tid >> 3;        // 0..31
  const int scol = (tid & 7) * 8;   // 0..56
  const u16* Ag = Xb + (size_t)(bm * 64 + srow) * HIDD + scol;
  const u16* Bg = Wt + (size_t)(bn * 128 + srow) * HIDD + scol;

  for (int k0 = 0; k0 < HIDD; k0 += 64) {
    if (k0) __syncthreads();
#pragma unroll
    for (int p = 0; p < 2; ++p) {
      const int r = srow + 32 * p;
      const int sw = (r & 7) << 3;
      *(u16x8*)&As[r * 64 + (scol ^ sw)] =
          *(const u16x8*)&Ag[(size_t)(32 * p) * HIDD + k0];
    }
#pragma unroll
    for (int p = 0; p < 4; ++p) {
      const int r = srow + 32 * p;
      const int sw = (r & 7) << 3;
      *(u16x8*)&Bs[r * 64 + (scol ^ sw)] =
          *(const u16x8*)&Bg[(size_t)(32 * p) * HIDD + k0];
    }
    __syncthreads();

    bf8 af[2][2], bfr[4][2];
#pragma unroll
    for (int f = 0; f < 2; ++f)
#pragma unroll
      for (int kk = 0; kk < 2; ++kk)
        af[f][kk] = ldfrag(As, wm + 16 * f + ln, kk * 32 + g * 8);
#pragma unroll
    for (int f = 0; f < 4; ++f)
#pragma unroll
      for (int kk = 0; kk < 2; ++kk)
        bfr[f][kk] = ldfrag(Bs, wn + 16 * f + ln, kk * 32 + g * 8);
    if (zi < 2) {  // transposed output frags
#pragma unroll
      for (int mf = 0; mf < 2; ++mf)
#pragma unroll
        for (int nf = 0; nf < 4; ++nf)
#pragma unroll
          for (int kk = 0; kk < 2; ++kk)
            acc[mf][nf] = __builtin_amdgcn_mfma_f32_16x16x32_bf16(
                bfr[nf][kk], af[mf][kk], acc[mf][nf], 0, 0, 0);
    } else {
#pragma unroll
      for (int mf = 0; mf < 2; ++mf)
#pragma unroll
        for (int nf = 0; nf < 4; ++nf)
#pragma unroll
          for (int kk = 0; kk < 2; ++kk)
            acc[mf][nf] = __builtin_amdgcn_mfma_f32_16x16x32_bf16(
                af[mf][kk], bfr[nf][kk], acc[mf][nf], 0, 0, 0);
    }
  }

  const int mrow  = bm * 64 + wm;
  const int nbase = (bn % 6) * 128 + wn;  // multiple of 64 within zi
  const int h     = nbase >> 6;

  if (zi < 2) {
    const float* __restrict__ bias = zi ? bk : bq;
    u16* __restrict__ outp = zi ? kb : qb;
#pragma unroll
    for (int nf = 0; nf < 4; ++nf) {
      const int d0 = 16 * nf + 4 * g;           // d within head
      float4 bi = *(const float4*)&bias[nbase + d0];
#pragma unroll
      for (int mf = 0; mf < 2; ++mf) {
        const int m = mrow + 16 * mf + ln;      // token index
        const int b = m >> 10, s = m & 1023;
        u16x4 o;
        o[0] = f2bf(acc[mf][nf][0] + bi.x);
        o[1] = f2bf(acc[mf][nf][1] + bi.y);
        o[2] = f2bf(acc[mf][nf][2] + bi.z);
        o[3] = f2bf(acc[mf][nf][3] + bi.w);
        *(u16x4*)&outp[(((size_t)(b * NHH + h)) * SS + s) * HDD + d0] = o;
      }
    }
  } else {
#pragma unroll
    for (int nf = 0; nf < 4; ++nf) {
      const int d = 16 * nf + ln;
      const float bi = bv[nbase + d];
#pragma unroll
      for (int mf = 0; mf < 2; ++mf) {
        const int m = mrow + 16 * mf + 4 * g;   // 4 consecutive tokens
        const int b = m >> 10, s = m & 1023;
        u16x4 o;
        o[0] = f2bf(acc[mf][nf][0] + bi);
        o[1] = f2bf(acc[mf][nf][1] + bi);
        o[2] = f2bf(acc[mf][nf][2] + bi);
        o[3] = f2bf(acc[mf][nf][3] + bi);
        *(u16x4*)&vt[(((size_t)(b * NHH + h)) * HDD + d) * SS + s] = o;
      }
    }
  }
}

// ---------------------------------------------------------------------------
// MFMA dual-branch flash attention, in-block split-K.
// Block = 32 q-rows, 4 waves. Wave w: pair p=w>>1 handles r in [512p,512p+512),
// sub-block wp=w&1 handles q-rows l0+16*wp..+15. Toeplitz bias via register
// MFMA + shuffle gather (no LDS). E-fragments read directly from global (L2).
// Final cross-pair softmax merge via LDS scratch.
// ---------------------------------------------------------------------------
__global__ __launch_bounds__(256) void attn_kernel(
    const u16* __restrict__ qbg,     // [B*NH][S][64] bf16
    const u16* __restrict__ kbg,     // [B*NH][S][64] bf16
    const u16* __restrict__ vtg,     // [B*NH][64][S] bf16
    const u16* __restrict__ eb,      // [2047][64] bf16
    const float* __restrict__ am,    // [B][S]
    const float* __restrict__ smask, // [S][S]
    const float* __restrict__ selp,  // [B][S]
    float* __restrict__ out) {       // [B][S][768]
  const int l0 = blockIdx.x * 32;
  const int h  = blockIdx.y;
  const int b  = blockIdx.z;
  const int bh = b * NHH + h;
  const size_t hoff = (size_t)bh * SS * HDD;

  // 48KB flat LDS: ks[2][4096] | vs[2][4096] | ps1[4][1024] | ps2[4][1024]
  __shared__ __align__(16) u16 smbuf[24576];
  u16* ks  = smbuf;           // per-pair K tile  [r][d] swizzled
  u16* vs  = smbuf + 8192;    // per-pair V^T tile [d][r] swizzled
  u16* ps1 = smbuf + 16384;   // per-wave P (branch 1)
  u16* ps2 = smbuf + 20480;   // per-wave P (branch 2)

  const int tid  = threadIdx.x;
  const int lane = tid & 63;
  const int w    = tid >> 6;   // 0..3
  const int p    = w >> 1;     // r-half
  const int wp   = w & 1;      // q-row sub-block
  const int g    = lane >> 4;
  const int ln   = lane & 15;

  // Q A-fragments (rows l0+16*wp+ln, k = 32*kk + 8g + j)
  bf8 qf[2];
  {
    const u16* qp = qbg + hoff + (size_t)(l0 + 16 * wp + ln) * HDD + g * 8;
    qf[0] = *(const bf8*)(qp);
    qf[1] = *(const bf8*)(qp + 32);
  }

  f32x4 acc1[4] = {}, acc2[4] = {};
  float m1[4], m2[4], sum1[4], sum2[4];
#pragma unroll
  for (int i = 0; i < 4; ++i) {
    m1[i] = -INFINITY; m2[i] = -INFINITY; sum1[i] = 0.f; sum2[i] = 0.f;
  }

  const int tid128 = tid & 127;
  const int rr = tid128 >> 2;          // 0..31
  const int cc = (tid128 & 3) << 4;    // 0,16,32,48
  u16* ksw = ks + p * 4096;
  u16* vsw = vs + p * 4096;
  u16* p1w = ps1 + w * 1024;
  u16* p2w = ps2 + w * 1024;

  for (int t = 0; t < 8; ++t) {
    const int r0 = 512 * p + 64 * t;
    __syncthreads();  // prev-iter LDS readers done
    {
      const u16* kgp = kbg + hoff + (size_t)r0 * HDD;
      const u16* vgp = vtg + hoff + r0;
#pragma unroll
      for (int pp = 0; pp < 2; ++pp) {
        const int r = rr + 32 * pp;
        const int sw = (r & 7) << 3;
        u16x8 a0 = *(const u16x8*)&kgp[(size_t)r * HDD + cc];
        u16x8 a1 = *(const u16x8*)&kgp[(size_t)r * HDD + cc + 8];
        *(u16x8*)&ksw[r * 64 + (cc ^ sw)] = a0;
        *(u16x8*)&ksw[r * 64 + ((cc + 8) ^ sw)] = a1;
        u16x8 c0 = *(const u16x8*)&vgp[(size_t)r * SS + cc];
        u16x8 c1 = *(const u16x8*)&vgp[(size_t)r * SS + cc + 8];
        *(u16x8*)&vsw[r * 64 + (cc ^ sw)] = c0;
        *(u16x8*)&vsw[r * 64 + ((cc + 8) ^ sw)] = c1;
      }
    }
    // masks (global, L2/L3-resident) — issue before barrier
    float amv[4], smv[4][4];
#pragma unroll
    for (int ct = 0; ct < 4; ++ct) {
      amv[ct] = am[(b << 10) + r0 + 16 * ct + ln];
#pragma unroll
      for (int i = 0; i < 4; ++i)
        smv[ct][i] =
            smask[(size_t)(l0 + 16 * wp + 4 * g + i) * SS + r0 + 16 * ct + ln];
    }
    __syncthreads();

    // QK^T: 16x64 scores
    f32x4 sc[4];
    __builtin_amdgcn_s_setprio(1);
#pragma unroll
    for (int ct = 0; ct < 4; ++ct) {
      f32x4 x = {0.f, 0.f, 0.f, 0.f};
#pragma unroll
      for (int kk = 0; kk < 2; ++kk)
        x = __builtin_amdgcn_mfma_f32_16x16x32_bf16(
            qf[kk], ldfrag(ksw, ct * 16 + ln, kk * 32 + g * 8), x, 0, 0, 0);
      sc[ct] = x;
    }

    // T = Q @ E_window^T (16x80), E B-fragments direct from global (L2)
    const int ebase = l0 - r0 + 960 + 16 * wp;
    f32x4 x5[5];
#pragma unroll
    for (int c5 = 0; c5 < 5; ++c5) {
      const int gr = min(max(ebase + c5 * 16 + ln, 0), 2046);
      const u16* ep = eb + (size_t)gr * HDD + g * 8;
      f32x4 x = {0.f, 0.f, 0.f, 0.f};
      x = __builtin_amdgcn_mfma_f32_16x16x32_bf16(qf[0], *(const bf8*)ep, x, 0, 0, 0);
      x = __builtin_amdgcn_mfma_f32_16x16x32_bf16(qf[1], *(const bf8*)(ep + 32), x, 0, 0, 0);
      x5[c5] = x;
    }
    __builtin_amdgcn_s_setprio(0);

    // bias gather (register shuffle), dual online softmax
#pragma unroll
    for (int i = 0; i < 4; ++i) {
      const int ll = 4 * g + i;
      // T[ll][col], col = ll+63-16ct-ln: plane = (3-ct)+(ln<ll), lane
      // reflection s = (ll+15-ln)&15 within the 16-lane group.
      const int srcIdx = (lane & 48) | ((ll + 15 - ln) & 15);
      const float y0 = __shfl(x5[0][i], srcIdx, 64);
      const float y1 = __shfl(x5[1][i], srcIdx, 64);
      const float y2 = __shfl(x5[2][i], srcIdx, 64);
      const float y3 = __shfl(x5[3][i], srcIdx, 64);
      const float y4 = __shfl(x5[4][i], srcIdx, 64);
      const bool hi = ln < ll;
      float tb[4];
      tb[0] = hi ? y4 : y3;
      tb[1] = hi ? y3 : y2;
      tb[2] = hi ? y2 : y1;
      tb[3] = hi ? y1 : y0;

      float s1r[4], s2r[4];
#pragma unroll
      for (int ct = 0; ct < 4; ++ct) {
        const float s1 = (sc[ct][i] + tb[ct]) * 0.125f + amv[ct];
        s1r[ct] = s1;
        s2r[ct] = s1 * smv[ct][i] + amv[ct];
      }
      // branch 1
      {
        float mx = fmaxf(fmaxf(s1r[0], s1r[1]), fmaxf(s1r[2], s1r[3]));
#pragma unroll
        for (int off = 1; off < 16; off <<= 1) mx = fmaxf(mx, __shfl_xor(mx, off, 64));
        const float mn = fmaxf(m1[i], mx);
        const float scale = __expf(m1[i] - mn);
        float rs = 0.f;
#pragma unroll
        for (int ct = 0; ct < 4; ++ct) {
          const float pr = __expf(s1r[ct] - mn);
          const int c = 16 * ct + ln;
          p1w[ll * 64 + (c ^ ((ll & 7) << 3))] = f2bf(pr);
          rs += pr;
        }
#pragma unroll
        for (int off = 1; off < 16; off <<= 1) rs += __shfl_xor(rs, off, 64);
        sum1[i] = sum1[i] * scale + rs;
        m1[i] = mn;
#pragma unroll
        for (int dt = 0; dt < 4; ++dt) acc1[dt][i] *= scale;
      }
      // branch 2
      {
        float mx = fmaxf(fmaxf(s2r[0], s2r[1]), fmaxf(s2r[2], s2r[3]));
#pragma unroll
        for (int off = 1; off < 16; off <<= 1) mx = fmaxf(mx, __shfl_xor(mx, off, 64));
        const float mn = fmaxf(m2[i], mx);
        const float scale = __expf(m2[i] - mn);
        float rs = 0.f;
#pragma unroll
        for (int ct = 0; ct < 4; ++ct) {
          const float pr = __expf(s2r[ct] - mn);
          const int c = 16 * ct + ln;
          p2w[ll * 64 + (c ^ ((ll & 7) << 3))] = f2bf(pr);
          rs += pr;
        }
#pragma unroll
        for (int off = 1; off < 16; off <<= 1) rs += __shfl_xor(rs, off, 64);
        sum2[i] = sum2[i] * scale + rs;
        m2[i] = mn;
#pragma unroll
        for (int dt = 0; dt < 4; ++dt) acc2[dt][i] *= scale;
      }
    }
    // ps buffers are wave-private; same-wave write->read ordered by lgkmcnt.

    // PV for both branches (shared V fragments)
    __builtin_amdgcn_s_setprio(1);
#pragma unroll
    for (int kk = 0; kk < 2; ++kk) {
      bf8 pa = ldfrag(p1w, ln, kk * 32 + g * 8);
      bf8 pb = ldfrag(p2w, ln, kk * 32 + g * 8);
#pragma unroll
      for (int dt = 0; dt < 4; ++dt) {
        bf8 vb = ldfrag(vsw, dt * 16 + ln, kk * 32 + g * 8);
        acc1[dt] = __builtin_amdgcn_mfma_f32_16x16x32_bf16(pa, vb, acc1[dt], 0, 0, 0);
        acc2[dt] = __builtin_amdgcn_mfma_f32_16x16x32_bf16(pb, vb, acc2[dt], 0, 0, 0);
      }
    }
    __builtin_amdgcn_s_setprio(0);
  }

  // -------- cross-pair combine (split-K merge) --------
  __syncthreads();  // all LDS tile reads done
  float* scr = (float*)smbuf;  // 4224 floats = 16.9KB, overlaps dead ks/vs
  if (p == 1) {
#pragma unroll
    for (int i = 0; i < 4; ++i) {
      const int row = 4 * g + i;
#pragma unroll
      for (int dt = 0; dt < 4; ++dt) {
        scr[wp * 1024 + row * 64 + dt * 16 + ln] = acc1[dt][i];
        scr[2048 + wp * 1024 + row * 64 + dt * 16 + ln] = acc2[dt][i];
      }
      if (ln == 0) {
        const int sb = 4096 + (wp * 16 + row) * 4;
        scr[sb + 0] = m1[i];
        scr[sb + 1] = sum1[i];
        scr[sb + 2] = m2[i];
        scr[sb + 3] = sum2[i];
      }
    }
  }
  __syncthreads();
  if (p == 0) {
#pragma unroll
    for (int i = 0; i < 4; ++i) {
      const int row = 4 * g + i;
      const int lg  = l0 + 16 * wp + row;
      const int sb  = 4096 + (wp * 16 + row) * 4;
      const float mB1 = scr[sb + 0], sB1 = scr[sb + 1];
      const float mB2 = scr[sb + 2], sB2 = scr[sb + 3];
      const float M1 = fmaxf(m1[i], mB1);
      const float e1A = __expf(m1[i] - M1), e1B = __expf(mB1 - M1);
      const float inv1 = 1.f / (sum1[i] * e1A + sB1 * e1B);
      const float M2 = fmaxf(m2[i], mB2);
      const float e2A = __expf(m2[i] - M2), e2B = __expf(mB2 - M2);
      const float inv2 = 1.f / (sum2[i] * e2A + sB2 * e2B);
      const float se = selp[(b << 10) + lg];
#pragma unroll
      for (int dt = 0; dt < 4; ++dt) {
        const float aB1 = scr[wp * 1024 + row * 64 + dt * 16 + ln];
        const float aB2 = scr[2048 + wp * 1024 + row * 64 + dt * 16 + ln];
        const float o1 = (acc1[dt][i] * e1A + aB1 * e1B) * inv1;
        const float o2 = (acc2[dt][i] * e2A + aB2 * e2B) * inv2;
        out[((size_t)((b << 10) + lg)) * HIDD + h * HDD + dt * 16 + ln] =
            se * o2 + (1.f - se) * o1;
      }
    }
  }
}

extern "C" void kernel_launch(void* const* d_in, const int* in_sizes, int n_in,
                              void* d_out, int out_size, void* d_ws, size_t ws_size,
                              hipStream_t stream) {
  const float* hidden = (const float*)d_in[0];
  const float* am     = (const float*)d_in[1];
  const float* smask  = (const float*)d_in[2];
  const float* selp   = (const float*)d_in[3];
  const float* Wq     = (const float*)d_in[4];
  const float* bq     = (const float*)d_in[5];
  const float* Wk     = (const float*)d_in[6];
  const float* bk     = (const float*)d_in[7];
  const float* Wv     = (const float*)d_in[8];
  const float* bv     = (const float*)d_in[9];
  const float* demb   = (const float*)d_in[10];
  float* out = (float*)d_out;

  u16* wsp = (u16*)d_ws;
  const size_t NEL = (size_t)BB * NHH * SS * HDD;  // 1572864
  u16* Xb  = wsp;                        // 2048*768
  u16* Wt  = Xb + (size_t)2048 * HIDD;   // 2304*768
  u16* qbw = Wt + (size_t)3 * HIDD * HIDD;
  u16* kbw = qbw + NEL;
  u16* vtw = kbw + NEL;
  u16* ebw = vtw + NEL;                  // 2047*64

  xconv_kernel<<<768, 256, 0, stream>>>(hidden, Xb);
  dim3 gw(HIDD / 64, HIDD / 64, 3);
  wtconv_kernel<<<gw, 256, 0, stream>>>(Wq, Wk, Wv, Wt);
  econv_kernel<<<64, 256, 0, stream>>>(demb, ebw);

  dim3 g1(18, 32);
  qkv_mfma_kernel<<<g1, 256, 0, stream>>>(Xb, Wt, bq, bk, bv, qbw, kbw, vtw);

  dim3 g2(SS / 32, NHH, BB);
  attn_kernel<<<g2, 256, 0, stream>>>(qbw, kbw, vtw, ebw, am, smask, selp, out);
}

// Round 5
// 101.971 us; speedup vs baseline: 1.0344x; 1.0344x over previous
//
#include <hip/hip_runtime.h>
#include <hip/hip_bf16.h>
#include <math.h>

#define BB   2
#define SS   1024
#define HIDD 768
#define NHH  12
#define HDD  64

typedef float f32x4 __attribute__((ext_vector_type(4)));
typedef short bf8   __attribute__((ext_vector_type(8)));   // 8 bf16 (bit pattern)
typedef unsigned short u16;
typedef unsigned int u32;
typedef u16 u16x8 __attribute__((ext_vector_type(8)));
typedef u16 u16x4 __attribute__((ext_vector_type(4)));

__device__ __forceinline__ u16 f2bf(float x) {  // RNE f32->bf16
  unsigned int u = __float_as_uint(x);
  u += 0x7fffu + ((u >> 16) & 1u);
  return (u16)(u >> 16);
}
__device__ __forceinline__ float bf2f(u16 x) {
  return __uint_as_float(((u32)x) << 16);
}

// Swizzled fragment read from a [R][64] bf16 LDS tile (XOR swizzle, 8-elem
// granularity). row = M/N index; kc = starting k element (multiple of 8).
__device__ __forceinline__ bf8 ldfrag(const u16* t, int row, int kc) {
  return *(const bf8*)&t[row * 64 + (kc ^ ((row & 7) << 3))];
}

// ---------------------------------------------------------------------------
// Prep: X f32 -> bf16 (same layout).
// ---------------------------------------------------------------------------
__global__ __launch_bounds__(256) void xconv_kernel(const float* __restrict__ X,
                                                    u16* __restrict__ Xb) {
  int i = (blockIdx.x * 256 + threadIdx.x) * 8;
  float4 a = *(const float4*)&X[i];
  float4 b = *(const float4*)&X[i + 4];
  u16x8 o;
  o[0] = f2bf(a.x); o[1] = f2bf(a.y); o[2] = f2bf(a.z); o[3] = f2bf(a.w);
  o[4] = f2bf(b.x); o[5] = f2bf(b.y); o[6] = f2bf(b.z); o[7] = f2bf(b.w);
  *(u16x8*)&Xb[i] = o;
}

// ---------------------------------------------------------------------------
// Prep: W [k][n] f32 (x3) -> Wt [3*768 rows n][768 cols k] bf16 (transposed).
// ---------------------------------------------------------------------------
__global__ __launch_bounds__(256) void wtconv_kernel(
    const float* __restrict__ Wq, const float* __restrict__ Wk,
    const float* __restrict__ Wv, u16* __restrict__ Wt) {
  const int zi = blockIdx.z;
  const float* __restrict__ W = (zi == 0) ? Wq : (zi == 1 ? Wk : Wv);
  const int n0 = blockIdx.x * 64;
  const int k0 = blockIdx.y * 64;
  __shared__ float t[64][65];
  const int tid = threadIdx.x;
  {
    const int kl = tid >> 4;
    const int nl = (tid & 15) * 4;
#pragma unroll
    for (int p = 0; p < 4; ++p) {
      float4 v = *(const float4*)&W[(size_t)(k0 + kl + 16 * p) * HIDD + n0 + nl];
      t[kl + 16 * p][nl + 0] = v.x;
      t[kl + 16 * p][nl + 1] = v.y;
      t[kl + 16 * p][nl + 2] = v.z;
      t[kl + 16 * p][nl + 3] = v.w;
    }
  }
  __syncthreads();
  {
    const int nl = tid >> 4;
    const int cl = (tid & 15) * 4;
#pragma unroll
    for (int p = 0; p < 4; ++p) {
      const int n = nl + 16 * p;
      u16x4 o;
      o[0] = f2bf(t[cl + 0][n]);
      o[1] = f2bf(t[cl + 1][n]);
      o[2] = f2bf(t[cl + 2][n]);
      o[3] = f2bf(t[cl + 3][n]);
      *(u16x4*)&Wt[(size_t)(zi * HIDD + n0 + n) * HIDD + k0 + cl] = o;
    }
  }
}

// ---------------------------------------------------------------------------
// Prep: dist_emb f32 -> bf16.
// ---------------------------------------------------------------------------
__global__ __launch_bounds__(256) void econv_kernel(const float* __restrict__ demb,
                                                    u16* __restrict__ eb) {
  int i = (blockIdx.x * 256 + threadIdx.x) * 8;
  if (i < 2047 * HDD) {
    float4 a = *(const float4*)&demb[i];
    float4 b = *(const float4*)&demb[i + 4];
    u16x8 o;
    o[0] = f2bf(a.x); o[1] = f2bf(a.y); o[2] = f2bf(a.z); o[3] = f2bf(a.w);
    o[4] = f2bf(b.x); o[5] = f2bf(b.y); o[6] = f2bf(b.z); o[7] = f2bf(b.w);
    *(u16x8*)&eb[i] = o;
  }
}

// ---------------------------------------------------------------------------
// Fused QKV MFMA GEMM (unchanged from R4).
// ---------------------------------------------------------------------------
__global__ __launch_bounds__(256) void qkv_mfma_kernel(
    const u16* __restrict__ Xb,   // [2048][768]
    const u16* __restrict__ Wt,   // [2304][768]
    const float* __restrict__ bq, const float* __restrict__ bk,
    const float* __restrict__ bv,
    u16* __restrict__ qb, u16* __restrict__ kb, u16* __restrict__ vt) {
  const int bn = blockIdx.x;   // 0..17  (128 N-cols each)
  const int bm = blockIdx.y;   // 0..31  (64 M-rows each)
  const int zi = bn / 6;

  __shared__ u16 As[64 * 64];
  __shared__ u16 Bs[128 * 64];

  const int tid  = threadIdx.x;
  const int lane = tid & 63;
  const int w    = tid >> 6;
  const int g    = lane >> 4;
  const int ln   = lane & 15;
  const int wm   = (w >> 1) * 32;
  const int wn   = (w & 1) * 64;

  f32x4 acc[2][4] = {};

  const int srow = tid >> 3;        // 0..31
  const int scol = (tid & 7) * 8;   // 0..56
  const u16* Ag = Xb + (size_t)(bm * 64 + srow) * HIDD + scol;
  const u16* Bg = Wt + (size_t)(bn * 128 + srow) * HIDD + scol;

  for (int k0 = 0; k0 < HIDD; k0 += 64) {
    if (k0) __syncthreads();
#pragma unroll
    for (int p = 0; p < 2; ++p) {
      const int r = srow + 32 * p;
      const int sw = (r & 7) << 3;
      *(u16x8*)&As[r * 64 + (scol ^ sw)] =
          *(const u16x8*)&Ag[(size_t)(32 * p) * HIDD + k0];
    }
#pragma unroll
    for (int p = 0; p < 4; ++p) {
      const int r = srow + 32 * p;
      const int sw = (r & 7) << 3;
      *(u16x8*)&Bs[r * 64 + (scol ^ sw)] =
          *(const u16x8*)&Bg[(size_t)(32 * p) * HIDD + k0];
    }
    __syncthreads();

    bf8 af[2][2], bfr[4][2];
#pragma unroll
    for (int f = 0; f < 2; ++f)
#pragma unroll
      for (int kk = 0; kk < 2; ++kk)
        af[f][kk] = ldfrag(As, wm + 16 * f + ln, kk * 32 + g * 8);
#pragma unroll
    for (int f = 0; f < 4; ++f)
#pragma unroll
      for (int kk = 0; kk < 2; ++kk)
        bfr[f][kk] = ldfrag(Bs, wn + 16 * f + ln, kk * 32 + g * 8);
    if (zi < 2) {  // transposed output frags
#pragma unroll
      for (int mf = 0; mf < 2; ++mf)
#pragma unroll
        for (int nf = 0; nf < 4; ++nf)
#pragma unroll
          for (int kk = 0; kk < 2; ++kk)
            acc[mf][nf] = __builtin_amdgcn_mfma_f32_16x16x32_bf16(
                bfr[nf][kk], af[mf][kk], acc[mf][nf], 0, 0, 0);
    } else {
#pragma unroll
      for (int mf = 0; mf < 2; ++mf)
#pragma unroll
        for (int nf = 0; nf < 4; ++nf)
#pragma unroll
          for (int kk = 0; kk < 2; ++kk)
            acc[mf][nf] = __builtin_amdgcn_mfma_f32_16x16x32_bf16(
                af[mf][kk], bfr[nf][kk], acc[mf][nf], 0, 0, 0);
    }
  }

  const int mrow  = bm * 64 + wm;
  const int nbase = (bn % 6) * 128 + wn;  // multiple of 64 within zi
  const int h     = nbase >> 6;

  if (zi < 2) {
    const float* __restrict__ bias = zi ? bk : bq;
    u16* __restrict__ outp = zi ? kb : qb;
#pragma unroll
    for (int nf = 0; nf < 4; ++nf) {
      const int d0 = 16 * nf + 4 * g;           // d within head
      float4 bi = *(const float4*)&bias[nbase + d0];
#pragma unroll
      for (int mf = 0; mf < 2; ++mf) {
        const int m = mrow + 16 * mf + ln;      // token index
        const int b = m >> 10, s = m & 1023;
        u16x4 o;
        o[0] = f2bf(acc[mf][nf][0] + bi.x);
        o[1] = f2bf(acc[mf][nf][1] + bi.y);
        o[2] = f2bf(acc[mf][nf][2] + bi.z);
        o[3] = f2bf(acc[mf][nf][3] + bi.w);
        *(u16x4*)&outp[(((size_t)(b * NHH + h)) * SS + s) * HDD + d0] = o;
      }
    }
  } else {
#pragma unroll
    for (int nf = 0; nf < 4; ++nf) {
      const int d = 16 * nf + ln;
      const float bi = bv[nbase + d];
#pragma unroll
      for (int mf = 0; mf < 2; ++mf) {
        const int m = mrow + 16 * mf + 4 * g;   // 4 consecutive tokens
        const int b = m >> 10, s = m & 1023;
        u16x4 o;
        o[0] = f2bf(acc[mf][nf][0] + bi);
        o[1] = f2bf(acc[mf][nf][1] + bi);
        o[2] = f2bf(acc[mf][nf][2] + bi);
        o[3] = f2bf(acc[mf][nf][3] + bi);
        *(u16x4*)&vt[(((size_t)(b * NHH + h)) * HDD + d) * SS + s] = o;
      }
    }
  }
}

// ---------------------------------------------------------------------------
// MFMA dual-branch flash attention, swapped-operand QK (scores: q = lane col),
// in-register softmax + P-fragment exchange via shuffles, Toeplitz bias via
// swapped T-GEMM + per-wave bf16 LDS gather. In-block split-K (2 pairs).
// ---------------------------------------------------------------------------
__global__ __launch_bounds__(256, 3) void attn_kernel(
    const u16* __restrict__ qbg,     // [B*NH][S][64] bf16
    const u16* __restrict__ kbg,     // [B*NH][S][64] bf16
    const u16* __restrict__ vtg,     // [B*NH][64][S] bf16
    const u16* __restrict__ eb,      // [2047][64] bf16
    const float* __restrict__ am,    // [B][S]
    const float* __restrict__ smask, // [S][S]
    const float* __restrict__ selp,  // [B][S]
    float* __restrict__ out) {       // [B][S][768]
  const int l0 = blockIdx.x * 32;
  const int h  = blockIdx.y;
  const int b  = blockIdx.z;
  const int bh = b * NHH + h;
  const size_t hoff = (size_t)bh * SS * HDD;

  // 32KB: ks[2][4096] | vs[2][4096]; + per-wave T buffers 10.9KB
  __shared__ __align__(16) u16 smbuf[16384];
  __shared__ __align__(4)  u16 tbuf[4 * 80 * 17];  // [wave][e][q], bf16

  const int tid  = threadIdx.x;
  const int lane = tid & 63;
  const int w    = tid >> 6;   // 0..3
  const int p    = w >> 1;     // r-half
  const int wp   = w & 1;      // q-row sub-block
  const int g    = lane >> 4;
  const int ln   = lane & 15;

  u16* ksw = smbuf + p * 4096;
  u16* vsw = smbuf + 8192 + p * 4096;
  u16* Tw  = tbuf + w * (80 * 17);

  // Q fragments (rows l0+16*wp+ln, k = 32*kk + 8g + j) — used as B-operand
  bf8 qf[2];
  {
    const u16* qp = qbg + hoff + (size_t)(l0 + 16 * wp + ln) * HDD + g * 8;
    qf[0] = *(const bf8*)(qp);
    qf[1] = *(const bf8*)(qp + 32);
  }

  f32x4 acc1[4] = {}, acc2[4] = {};
  // per-lane stats for q = l0+16*wp+ln
  float m1 = -INFINITY, m2 = -INFINITY, sum1 = 0.f, sum2 = 0.f;

  const int tid128 = tid & 127;
  const int rr = tid128 >> 2;          // 0..31
  const int cc = (tid128 & 3) << 4;    // 0,16,32,48
  const int S0i = ((lane & 16) << 1) | ln;  // 32*(g&1)+ln
  const int S1i = S0i + 16;
  const bool ghi = (lane & 32) != 0;        // g >= 2

  for (int t = 0; t < 8; ++t) {
    const int r0 = 512 * p + 64 * t;
    __syncthreads();  // prev-iter LDS readers done

    // E fragments for T-GEMM, direct from global (L2): issue early
    const int W0 = l0 + 16 * wp - r0 + 960;
    bf8 ef[5][2];
#pragma unroll
    for (int c5 = 0; c5 < 5; ++c5) {
      const int gr = min(W0 + 16 * c5 + ln, 2046);
      const u16* ep = eb + (size_t)gr * HDD + g * 8;
      ef[c5][0] = *(const bf8*)(ep);
      ef[c5][1] = *(const bf8*)(ep + 32);
    }
    // masks: r = r0+16*ct+4*g+i, q-row = l0+16*wp+ln
    f32x4 amv[4], smv[4];
#pragma unroll
    for (int ct = 0; ct < 4; ++ct) {
      amv[ct] = *(const f32x4*)&am[(b << 10) + r0 + 16 * ct + 4 * g];
      smv[ct] = *(const f32x4*)&smask[(size_t)(l0 + 16 * wp + ln) * SS +
                                      r0 + 16 * ct + 4 * g];
    }
    // stage K/V (pair-cooperative)
    {
      const u16* kgp = kbg + hoff + (size_t)r0 * HDD;
      const u16* vgp = vtg + hoff + r0;
#pragma unroll
      for (int pp = 0; pp < 2; ++pp) {
        const int r = rr + 32 * pp;
        const int sw = (r & 7) << 3;
        u16x8 a0 = *(const u16x8*)&kgp[(size_t)r * HDD + cc];
        u16x8 a1 = *(const u16x8*)&kgp[(size_t)r * HDD + cc + 8];
        *(u16x8*)&ksw[r * 64 + (cc ^ sw)] = a0;
        *(u16x8*)&ksw[r * 64 + ((cc + 8) ^ sw)] = a1;
        u16x8 c0 = *(const u16x8*)&vgp[(size_t)r * SS + cc];
        u16x8 c1 = *(const u16x8*)&vgp[(size_t)r * SS + cc + 8];
        *(u16x8*)&vsw[r * 64 + (cc ^ sw)] = c0;
        *(u16x8*)&vsw[r * 64 + ((cc + 8) ^ sw)] = c1;
      }
    }
    __syncthreads();

    __builtin_amdgcn_s_setprio(1);
    // T_sw = mfma(E, Q): lane (g,ln) gets T[16c5+4g+i][q=ln] -> LDS
#pragma unroll
    for (int c5 = 0; c5 < 5; ++c5) {
      f32x4 x = {0.f, 0.f, 0.f, 0.f};
      x = __builtin_amdgcn_mfma_f32_16x16x32_bf16(ef[c5][0], qf[0], x, 0, 0, 0);
      x = __builtin_amdgcn_mfma_f32_16x16x32_bf16(ef[c5][1], qf[1], x, 0, 0, 0);
#pragma unroll
      for (int i = 0; i < 4; ++i)
        Tw[(16 * c5 + 4 * g + i) * 17 + ln] = f2bf(x[i]);
    }
    // QK^T swapped: sc[ct][i] = S[r=16ct+4g+i][q=ln]
    f32x4 sc[4];
#pragma unroll
    for (int ct = 0; ct < 4; ++ct) {
      f32x4 x = {0.f, 0.f, 0.f, 0.f};
#pragma unroll
      for (int kk = 0; kk < 2; ++kk)
        x = __builtin_amdgcn_mfma_f32_16x16x32_bf16(
            ldfrag(ksw, ct * 16 + ln, kk * 32 + g * 8), qf[kk], x, 0, 0, 0);
      sc[ct] = x;
    }
    __builtin_amdgcn_s_setprio(0);

    // scores + Toeplitz bias (column-local T gather)
    float s1r[4][4], s2r[4][4];
#pragma unroll
    for (int ct = 0; ct < 4; ++ct)
#pragma unroll
      for (int i = 0; i < 4; ++i) {
        const int e = ln + 63 - 16 * ct - 4 * g - i;
        const float tb = bf2f(Tw[e * 17 + ln]);
        const float s1 = (sc[ct][i] + tb) * 0.125f + amv[ct][i];
        s1r[ct][i] = s1;
        s2r[ct][i] = s1 * smv[ct][i] + amv[ct][i];
      }

    bf8 pa1[2], pa2[2];
    // ---- branch 1 softmax ----
    {
      float mx = s1r[0][0];
#pragma unroll
      for (int ct = 0; ct < 4; ++ct)
#pragma unroll
        for (int i = 0; i < 4; ++i) mx = fmaxf(mx, s1r[ct][i]);
      mx = fmaxf(mx, __shfl_xor(mx, 16, 64));
      mx = fmaxf(mx, __shfl_xor(mx, 32, 64));
      const float mn = fmaxf(m1, mx);
      const float scl = __expf(m1 - mn);
      m1 = mn;
      float rs = 0.f;
      u32 pk[4][2];
#pragma unroll
      for (int ct = 0; ct < 4; ++ct) {
        const float p0 = __expf(s1r[ct][0] - mn);
        const float p1 = __expf(s1r[ct][1] - mn);
        const float p2 = __expf(s1r[ct][2] - mn);
        const float p3 = __expf(s1r[ct][3] - mn);
        rs += (p0 + p1) + (p2 + p3);
        pk[ct][0] = (u32)f2bf(p0) | ((u32)f2bf(p1) << 16);
        pk[ct][1] = (u32)f2bf(p2) | ((u32)f2bf(p3) << 16);
      }
      rs += __shfl_xor(rs, 16, 64);
      rs += __shfl_xor(rs, 32, 64);
      sum1 = sum1 * scl + rs;
#pragma unroll
      for (int i = 0; i < 4; ++i) {
        const float s = __shfl(scl, (lane & 48) + 4 * g + i, 64);
#pragma unroll
        for (int dt = 0; dt < 4; ++dt) acc1[dt][i] *= s;
      }
      // P A-fragment exchange
#pragma unroll
      for (int kk = 0; kk < 2; ++kk) {
        union { u32 u[4]; bf8 v; } f;
        const int cA = 2 * kk, cB = 2 * kk + 1;
        u32 a, bb;
        a = (u32)__shfl((int)pk[cA][0], S0i, 64);
        bb = (u32)__shfl((int)pk[cB][0], S0i, 64);
        f.u[0] = ghi ? bb : a;
        a = (u32)__shfl((int)pk[cA][1], S0i, 64);
        bb = (u32)__shfl((int)pk[cB][1], S0i, 64);
        f.u[1] = ghi ? bb : a;
        a = (u32)__shfl((int)pk[cA][0], S1i, 64);
        bb = (u32)__shfl((int)pk[cB][0], S1i, 64);
        f.u[2] = ghi ? bb : a;
        a = (u32)__shfl((int)pk[cA][1], S1i, 64);
        bb = (u32)__shfl((int)pk[cB][1], S1i, 64);
        f.u[3] = ghi ? bb : a;
        pa1[kk] = f.v;
      }
    }
    // ---- branch 2 softmax ----
    {
      float mx = s2r[0][0];
#pragma unroll
      for (int ct = 0; ct < 4; ++ct)
#pragma unroll
        for (int i = 0; i < 4; ++i) mx = fmaxf(mx, s2r[ct][i]);
      mx = fmaxf(mx, __shfl_xor(mx, 16, 64));
      mx = fmaxf(mx, __shfl_xor(mx, 32, 64));
      const float mn = fmaxf(m2, mx);
      const float scl = __expf(m2 - mn);
      m2 = mn;
      float rs = 0.f;
      u32 pk[4][2];
#pragma unroll
      for (int ct = 0; ct < 4; ++ct) {
        const float p0 = __expf(s2r[ct][0] - mn);
        const float p1 = __expf(s2r[ct][1] - mn);
        const float p2 = __expf(s2r[ct][2] - mn);
        const float p3 = __expf(s2r[ct][3] - mn);
        rs += (p0 + p1) + (p2 + p3);
        pk[ct][0] = (u32)f2bf(p0) | ((u32)f2bf(p1) << 16);
        pk[ct][1] = (u32)f2bf(p2) | ((u32)f2bf(p3) << 16);
      }
      rs += __shfl_xor(rs, 16, 64);
      rs += __shfl_xor(rs, 32, 64);
      sum2 = sum2 * scl + rs;
#pragma unroll
      for (int i = 0; i < 4; ++i) {
        const float s = __shfl(scl, (lane & 48) + 4 * g + i, 64);
#pragma unroll
        for (int dt = 0; dt < 4; ++dt) acc2[dt][i] *= s;
      }
#pragma unroll
      for (int kk = 0; kk < 2; ++kk) {
        union { u32 u[4]; bf8 v; } f;
        const int cA = 2 * kk, cB = 2 * kk + 1;
        u32 a, bb;
        a = (u32)__shfl((int)pk[cA][0], S0i, 64);
        bb = (u32)__shfl((int)pk[cB][0], S0i, 64);
        f.u[0] = ghi ? bb : a;
        a = (u32)__shfl((int)pk[cA][1], S0i, 64);
        bb = (u32)__shfl((int)pk[cB][1], S0i, 64);
        f.u[1] = ghi ? bb : a;
        a = (u32)__shfl((int)pk[cA][0], S1i, 64);
        bb = (u32)__shfl((int)pk[cB][0], S1i, 64);
        f.u[2] = ghi ? bb : a;
        a = (u32)__shfl((int)pk[cA][1], S1i, 64);
        bb = (u32)__shfl((int)pk[cB][1], S1i, 64);
        f.u[3] = ghi ? bb : a;
        pa2[kk] = f.v;
      }
    }

    // PV: O[q=4g+i][d=16dt+ln]
    __builtin_amdgcn_s_setprio(1);
#pragma unroll
    for (int kk = 0; kk < 2; ++kk) {
#pragma unroll
      for (int dt = 0; dt < 4; ++dt) {
        bf8 vb = ldfrag(vsw, dt * 16 + ln, kk * 32 + g * 8);
        acc1[dt] = __builtin_amdgcn_mfma_f32_16x16x32_bf16(pa1[kk], vb, acc1[dt], 0, 0, 0);
        acc2[dt] = __builtin_amdgcn_mfma_f32_16x16x32_bf16(pa2[kk], vb, acc2[dt], 0, 0, 0);
      }
    }
    __builtin_amdgcn_s_setprio(0);
  }

  // -------- cross-pair combine (split-K merge) --------
  __syncthreads();  // all LDS tile reads done
  float* scr = (float*)smbuf;  // 4224 floats, overlaps dead ks/vs
  if (p == 1) {
#pragma unroll
    for (int i = 0; i < 4; ++i) {
      const int row = 4 * g + i;
#pragma unroll
      for (int dt = 0; dt < 4; ++dt) {
        scr[wp * 1024 + row * 64 + dt * 16 + ln] = acc1[dt][i];
        scr[2048 + wp * 1024 + row * 64 + dt * 16 + ln] = acc2[dt][i];
      }
    }
    if (g == 0) {  // one lane per q-row publishes stats
      const int sb = 4096 + (wp * 16 + ln) * 4;
      scr[sb + 0] = m1;
      scr[sb + 1] = sum1;
      scr[sb + 2] = m2;
      scr[sb + 3] = sum2;
    }
  }
  __syncthreads();
  if (p == 0) {
    const int sb = 4096 + (wp * 16 + ln) * 4;
    const float mB1 = scr[sb + 0], sB1 = scr[sb + 1];
    const float mB2 = scr[sb + 2], sB2 = scr[sb + 3];
    const float M1 = fmaxf(m1, mB1);
    const float e1A = __expf(m1 - M1), e1B = __expf(mB1 - M1);
    const float inv1 = 1.f / (sum1 * e1A + sB1 * e1B);
    const float a1 = e1A * inv1, c1 = e1B * inv1;  // per-lane, q = ln
    const float M2 = fmaxf(m2, mB2);
    const float e2A = __expf(m2 - M2), e2B = __expf(mB2 - M2);
    const float inv2 = 1.f / (sum2 * e2A + sB2 * e2B);
    const float a2 = e2A * inv2, c2 = e2B * inv2;
#pragma unroll
    for (int i = 0; i < 4; ++i) {
      const int src = (lane & 48) + 4 * g + i;
      const float a1s = __shfl(a1, src, 64), c1s = __shfl(c1, src, 64);
      const float a2s = __shfl(a2, src, 64), c2s = __shfl(c2, src, 64);
      const int row = 4 * g + i;
      const int lg = l0 + 16 * wp + row;
      const float se = selp[(b << 10) + lg];
#pragma unroll
      for (int dt = 0; dt < 4; ++dt) {
        const float aB1 = scr[wp * 1024 + row * 64 + dt * 16 + ln];
        const float aB2 = scr[2048 + wp * 1024 + row * 64 + dt * 16 + ln];
        const float o1 = acc1[dt][i] * a1s + aB1 * c1s;
        const float o2 = acc2[dt][i] * a2s + aB2 * c2s;
        out[((size_t)((b << 10) + lg)) * HIDD + h * HDD + dt * 16 + ln] =
            se * o2 + (1.f - se) * o1;
      }
    }
  }
}

extern "C" void kernel_launch(void* const* d_in, const int* in_sizes, int n_in,
                              void* d_out, int out_size, void* d_ws, size_t ws_size,
                              hipStream_t stream) {
  const float* hidden = (const float*)d_in[0];
  const float* am     = (const float*)d_in[1];
  const float* smask  = (const float*)d_in[2];
  const float* selp   = (const float*)d_in[3];
  const float* Wq     = (const float*)d_in[4];
  const float* bq     = (const float*)d_in[5];
  const float* Wk     = (const float*)d_in[6];
  const float* bk     = (const float*)d_in[7];
  const float* Wv     = (const float*)d_in[8];
  const float* bv     = (const float*)d_in[9];
  const float* demb   = (const float*)d_in[10];
  float* out = (float*)d_out;

  u16* wsp = (u16*)d_ws;
  const size_t NEL = (size_t)BB * NHH * SS * HDD;  // 1572864
  u16* Xb  = wsp;                        // 2048*768
  u16* Wt  = Xb + (size_t)2048 * HIDD;   // 2304*768
  u16* qbw = Wt + (size_t)3 * HIDD * HIDD;
  u16* kbw = qbw + NEL;
  u16* vtw = kbw + NEL;
  u16* ebw = vtw + NEL;                  // 2047*64

  xconv_kernel<<<768, 256, 0, stream>>>(hidden, Xb);
  dim3 gw(HIDD / 64, HIDD / 64, 3);
  wtconv_kernel<<<gw, 256, 0, stream>>>(Wq, Wk, Wv, Wt);
  econv_kernel<<<64, 256, 0, stream>>>(demb, ebw);

  dim3 g1(18, 32);
  qkv_mfma_kernel<<<g1, 256, 0, stream>>>(Xb, Wt, bq, bk, bv, qbw, kbw, vtw);

  dim3 g2(SS / 32, NHH, BB);
  attn_kernel<<<g2, 256, 0, stream>>>(qbw, kbw, vtw, ebw, am, smask, selp, out);
}